// Round 2
// baseline (1034.167 us; speedup 1.0000x reference)
//
#include <hip/hip_runtime.h>
#include <cstddef>

#define BB 16
#define NK 2048
#define TK 4096
#define HH 256
#define H2 512

// ---------------- dec_fea = s_t_hat @ dec_proj_w + b  (16x256, tiny) --------
__global__ void k_dec_fea(const float* __restrict__ s_t_hat,
                          const float* __restrict__ Wd,
                          const float* __restrict__ bd,
                          float* __restrict__ dec_fea) {
    int b = blockIdx.x, d = threadIdx.x;
    __shared__ float s[H2];
    s[d]       = s_t_hat[b * H2 + d];
    s[d + HH]  = s_t_hat[b * H2 + HH + d];
    __syncthreads();
    float acc = bd[d];
    #pragma unroll 8
    for (int j = 0; j < H2; ++j) acc = fmaf(s[j], Wd[j * HH + d], acc);
    dec_fea[b * HH + d] = acc;
}

// ---------------- scores[b,k] = tanh(enc[b,k,:]@W + dec[b,:]) . v -----------
// Register-tiled: block = 32 nodes x 256 d. Thread (lane=d-quad, wave=node-octet)
// holds acc[8 nodes][4 d]. LDS enc reads are wave-broadcast, 16 FMA each.
__global__ __launch_bounds__(256) void k_scores(const float* __restrict__ enc,
                         const float* __restrict__ Wenc,
                         const float* __restrict__ dec_fea,
                         const float* __restrict__ v,
                         float* __restrict__ scores) {
    int b   = blockIdx.y;
    int k0  = blockIdx.x * 32;
    int tid = threadIdx.x;
    int lane = tid & 63;   // d-quad index: d = lane*4 .. +3
    int wv   = tid >> 6;   // node group: nodes wv*8 .. +7

    __shared__ float4 encSV[32 * 64];   // 32 nodes x 64 float4 = 32 KB
    const float4* baseV = (const float4*)(enc + ((size_t)b * NK + k0) * HH);
    #pragma unroll
    for (int r = 0; r < 8; ++r) encSV[r * 256 + tid] = baseV[r * 256 + tid];
    __syncthreads();

    const float4* Wv = (const float4*)Wenc;  // (256 h) x (64 d-quads)
    float4 acc[8];
    #pragma unroll
    for (int i = 0; i < 8; ++i) acc[i] = make_float4(0.f, 0.f, 0.f, 0.f);

    for (int h4 = 0; h4 < 64; ++h4) {
        float4 w0 = Wv[(h4 * 4 + 0) * 64 + lane];
        float4 w1 = Wv[(h4 * 4 + 1) * 64 + lane];
        float4 w2 = Wv[(h4 * 4 + 2) * 64 + lane];
        float4 w3 = Wv[(h4 * 4 + 3) * 64 + lane];
        #pragma unroll
        for (int i = 0; i < 8; ++i) {
            float4 e = encSV[(wv * 8 + i) * 64 + h4];  // broadcast
            acc[i].x = fmaf(e.x, w0.x, acc[i].x); acc[i].y = fmaf(e.x, w0.y, acc[i].y);
            acc[i].z = fmaf(e.x, w0.z, acc[i].z); acc[i].w = fmaf(e.x, w0.w, acc[i].w);
            acc[i].x = fmaf(e.y, w1.x, acc[i].x); acc[i].y = fmaf(e.y, w1.y, acc[i].y);
            acc[i].z = fmaf(e.y, w1.z, acc[i].z); acc[i].w = fmaf(e.y, w1.w, acc[i].w);
            acc[i].x = fmaf(e.z, w2.x, acc[i].x); acc[i].y = fmaf(e.z, w2.y, acc[i].y);
            acc[i].z = fmaf(e.z, w2.z, acc[i].z); acc[i].w = fmaf(e.z, w2.w, acc[i].w);
            acc[i].x = fmaf(e.w, w3.x, acc[i].x); acc[i].y = fmaf(e.w, w3.y, acc[i].y);
            acc[i].z = fmaf(e.w, w3.z, acc[i].z); acc[i].w = fmaf(e.w, w3.w, acc[i].w);
        }
    }

    float4 df = ((const float4*)(dec_fea + b * HH))[lane];
    float4 vv = ((const float4*)v)[lane];
    #pragma unroll
    for (int i = 0; i < 8; ++i) {
        float p = tanhf(acc[i].x + df.x) * vv.x
                + tanhf(acc[i].y + df.y) * vv.y
                + tanhf(acc[i].z + df.z) * vv.z
                + tanhf(acc[i].w + df.w) * vv.w;
        #pragma unroll
        for (int off = 32; off > 0; off >>= 1) p += __shfl_down(p, off, 64);
        if (lane == 0) scores[b * NK + k0 + wv * 8 + i] = p;
    }
}

// ---------------- masked softmax + renorm (max-shift cancels in renorm) -----
__global__ void k_softmax(const float* __restrict__ scores,
                          const float* __restrict__ mask,
                          float* __restrict__ attn) {
    int b = blockIdx.x, tid = threadIdx.x;
    int lane = tid & 63, wv = tid >> 6;
    __shared__ float redmax[4], redsum[4];
    float vals[8];
    float m = -1e30f;
    #pragma unroll
    for (int r = 0; r < 8; ++r) {
        vals[r] = scores[b * NK + r * 256 + tid];
        m = fmaxf(m, vals[r]);
    }
    #pragma unroll
    for (int off = 1; off < 64; off <<= 1) m = fmaxf(m, __shfl_xor(m, off, 64));
    if (lane == 0) redmax[wv] = m;
    __syncthreads();
    m = fmaxf(fmaxf(redmax[0], redmax[1]), fmaxf(redmax[2], redmax[3]));
    float s = 0.f;
    #pragma unroll
    for (int r = 0; r < 8; ++r) {
        float e = __expf(vals[r] - m) * mask[b * NK + r * 256 + tid];
        vals[r] = e;
        s += e;
    }
    #pragma unroll
    for (int off = 1; off < 64; off <<= 1) s += __shfl_xor(s, off, 64);
    if (lane == 0) redsum[wv] = s;
    __syncthreads();
    s = redsum[0] + redsum[1] + redsum[2] + redsum[3];
    float inv = 1.f / s;
    #pragma unroll
    for (int r = 0; r < 8; ++r) attn[b * NK + r * 256 + tid] = vals[r] * inv;
}

// ---------------- c_t partials: ctp[b][kc][h] = sum over 64 k ---------------
__global__ void k_ct(const float* __restrict__ attn,
                     const float* __restrict__ enc,
                     float* __restrict__ ctp) {
    int b = blockIdx.y;
    int kc = blockIdx.x;            // 32 chunks of 64 k
    int h = threadIdx.x;
    const float* e  = enc + ((size_t)b * NK + kc * 64) * HH;
    const float* wb = attn + b * NK + kc * 64;
    float acc = 0.f;
    #pragma unroll 8
    for (int k = 0; k < 64; ++k) acc = fmaf(wb[k], e[(size_t)k * HH + h], acc);
    ctp[((size_t)b * 32 + kc) * HH + h] = acc;
}

__global__ void k_ct_red(const float* __restrict__ ctp,
                         float* __restrict__ c_t) {
    int b = blockIdx.x, h = threadIdx.x;
    float s = 0.f;
    #pragma unroll
    for (int c = 0; c < 32; ++c) s += ctp[((size_t)b * 32 + c) * HH + h];
    c_t[b * HH + h] = s;
}

// ---------------- streamed w(b,k) x M(b,k,NCOLS) -> partials, no atomics ----
// WCH>0: weight itself arrives as WCH partial chunks (b,WCH,NK); reduce on load.
// REV: iterate k in reverse (pass-2 over graph starts on pass-1's L3 residue).
template <int NCOLS, int KCH, int WCH, bool REV>
__global__ __launch_bounds__(256) void k_vecmat_p(const float* __restrict__ w,
                         const float* __restrict__ M,
                         float* __restrict__ outp) {
    constexpr int KR = NK / KCH;
    int b  = blockIdx.z;
    int ky = blockIdx.y;
    int k0 = ky * KR;
    int t  = blockIdx.x * 1024 + threadIdx.x * 4;
    __shared__ float sw[KR];
    if (WCH == 0) {
        for (int i = threadIdx.x; i < KR; i += 256) sw[i] = w[b * NK + k0 + i];
    } else {
        for (int i = threadIdx.x; i < KR; i += 256) {
            float s = 0.f;
            #pragma unroll
            for (int c = 0; c < WCH; ++c)
                s += w[((size_t)b * WCH + c) * NK + k0 + i];
            sw[i] = s;
        }
    }
    __syncthreads();
    const float4* Mv = (const float4*)(M + (size_t)b * NK * NCOLS
                                         + (size_t)k0 * NCOLS) + (t >> 2);
    float4 acc = make_float4(0.f, 0.f, 0.f, 0.f);
    #pragma unroll 8
    for (int kk = 0; kk < KR; ++kk) {
        int k = REV ? (KR - 1 - kk) : kk;
        float a = sw[k];
        float4 vv = Mv[(size_t)k * (NCOLS / 4)];
        acc.x = fmaf(a, vv.x, acc.x);
        acc.y = fmaf(a, vv.y, acc.y);
        acc.z = fmaf(a, vv.z, acc.z);
        acc.w = fmaf(a, vv.w, acc.w);
    }
    *(float4*)(outp + ((size_t)b * KCH + ky) * NCOLS + t) = acc;
}

// ---------------- flow_out = (attn + oh + th) * 0.33333, reduce partials ----
__global__ void k_flowout(const float* __restrict__ attn,
                          const float* __restrict__ ohp,
                          const float* __restrict__ thp,
                          float* __restrict__ out) {
    int i = blockIdx.x * 256 + threadIdx.x;   // over b*NK
    int b = i >> 11, k = i & (NK - 1);
    float oh = 0.f, th = 0.f;
    #pragma unroll
    for (int c = 0; c < 32; ++c) {
        oh += ohp[((size_t)b * 32 + c) * NK + k];
        th += thp[((size_t)b * 32 + c) * NK + k];
    }
    out[i] = (attn[i] + oh + th) * 0.33333f;
}

// ---------------- tok normalize (reduce 16 partial chunks inline) -----------
__global__ void k_toknorm(const float* __restrict__ tokp,
                          float* __restrict__ out) {
    int b = blockIdx.x, tid = threadIdx.x;
    int lane = tid & 63, wv = tid >> 6;
    __shared__ float redsum[4];
    float vals[16];
    float s = 0.f;
    #pragma unroll
    for (int r = 0; r < 16; ++r) {
        int col = r * 256 + tid;
        float v = 0.f;
        #pragma unroll
        for (int c = 0; c < 16; ++c) v += tokp[((size_t)b * 16 + c) * TK + col];
        vals[r] = v;
        s += v;
    }
    #pragma unroll
    for (int off = 1; off < 64; off <<= 1) s += __shfl_xor(s, off, 64);
    if (lane == 0) redsum[wv] = s;
    __syncthreads();
    s = redsum[0] + redsum[1] + redsum[2] + redsum[3];
    float inv = 1.f / s;
    #pragma unroll
    for (int r = 0; r < 16; ++r) out[b * TK + r * 256 + tid] = vals[r] * inv;
}

extern "C" void kernel_launch(void* const* d_in, const int* in_sizes, int n_in,
                              void* d_out, int out_size, void* d_ws, size_t ws_size,
                              hipStream_t stream) {
    const float* s_t_hat = (const float*)d_in[0];
    const float* enc     = (const float*)d_in[1];
    const float* n2t     = (const float*)d_in[2];
    const float* mask    = (const float*)d_in[3];
    const float* graph   = (const float*)d_in[4];
    // d_in[5] flow, d_in[6] W_c_w: dead code in reference
    const float* Wenc    = (const float*)d_in[7];
    const float* Wdec    = (const float*)d_in[8];
    const float* bdec    = (const float*)d_in[9];
    const float* vnode   = (const float*)d_in[10];

    float* out = (float*)d_out;
    float* ws  = (float*)d_ws;

    // workspace layout (floats) — all partial buffers fully overwritten,
    // so no memset/poison-clear is needed anywhere.
    float* dec_fea = ws;              //      4096
    float* scores  = ws + 4096;       //     32768
    float* ctp     = ws + 36864;      //    131072 (16 x 32 x 256)
    float* ohp     = ws + 167936;     //   1048576 (16 x 32 x 2048)
    float* thp     = ws + 1216512;    //   1048576
    float* tokp    = ws + 2265088;    //   1048576 (16 x 16 x 4096)
                                      // total 3313664 floats = 13.3 MB

    // output layout (return order): c_t, attn, tok, flow_out
    float* c_t   = out;             //  4096
    float* attn  = out + 4096;      // 32768
    float* tok   = out + 36864;     // 65536
    float* flowo = out + 102400;    // 32768

    k_dec_fea<<<BB, 256, 0, stream>>>(s_t_hat, Wdec, bdec, dec_fea);
    k_scores<<<dim3(NK / 32, BB), 256, 0, stream>>>(enc, Wenc, dec_fea, vnode, scores);
    k_softmax<<<BB, 256, 0, stream>>>(scores, mask, attn);
    // c_t right after scores so enc (33 MB) is still L3-hot
    k_ct<<<dim3(32, BB), 256, 0, stream>>>(attn, enc, ctp);
    k_ct_red<<<BB, 256, 0, stream>>>(ctp, c_t);
    // graph pass 1 forward; pass 2 reversed-k to hit pass 1's L3 residue.
    // pass 2 reduces one_hop's 32 weight partials inline on load.
    k_vecmat_p<NK, 32, 0,  false><<<dim3(2, 32, BB), 256, 0, stream>>>(attn, graph, ohp);
    k_vecmat_p<NK, 32, 32, true ><<<dim3(2, 32, BB), 256, 0, stream>>>(ohp,  graph, thp);
    // flowout while ohp/thp are L2-hot
    k_flowout<<<(BB * NK) / 256, 256, 0, stream>>>(attn, ohp, thp, flowo);
    // big 512 MB node_to_token stream last
    k_vecmat_p<TK, 16, 0,  false><<<dim3(4, 16, BB), 256, 0, stream>>>(attn, n2t, tokp);
    k_toknorm<<<BB, 256, 0, stream>>>(tokp, tok);
}